// Round 1
// baseline (28358.447 us; speedup 1.0000x reference)
//
#include <hip/hip_runtime.h>
#include <math.h>

typedef __bf16 bf16x8 __attribute__((ext_vector_type(8)));
typedef float f32x4 __attribute__((ext_vector_type(4)));
typedef unsigned int u32x4 __attribute__((ext_vector_type(4)));

constexpr int QQ = 1027;   // states
constexpr int SS = 26;     // alphabet
constexpr int TT = 512;    // sequence length
constexpr int NB = 256;    // batch
constexpr int KP = 1056;   // K padded (mult of 32)
constexpr int NP = 1040;   // N padded (mult of 16)
constexpr int BTS = 1040;  // Bt row stride (floats), padded cols are 0
constexpr int AST = 1064;  // alpha LDS row stride (bf16 elems): 2128B, 16B-aligned
constexpr int WR = 16;     // batch rows per workgroup
constexpr int NWV = 13;    // waves per workgroup (65 col-tiles / 5 per wave)
constexpr int BLK = NWV * 64;
constexpr int KSTEPS = KP / 32;

__device__ __forceinline__ unsigned short f2bf(float f) {
  union { float f; unsigned u; } v; v.f = f;
  return (unsigned short)((v.u + 0x7fffu + ((v.u >> 16) & 1u)) >> 16);
}
__device__ __forceinline__ float bf2f(unsigned short h) {
  union { unsigned u; float f; } v; v.u = ((unsigned)h) << 16; return v.f;
}

__global__ void k_zero(u32x4* p, int n) {
  int i = blockIdx.x * blockDim.x + threadIdx.x;
  if (i < n) p[i] = (u32x4){0u, 0u, 0u, 0u};
}

__global__ void k_prep_init(const float* __restrict__ il, float* __restrict__ ip) {
  __shared__ float red[1024];
  int tid = threadIdx.x;
  float m = -1e30f;
  for (int q = tid; q < QQ; q += 1024) m = fmaxf(m, il[q]);
  red[tid] = m; __syncthreads();
  for (int off = 512; off > 0; off >>= 1) {
    if (tid < off) red[tid] = fmaxf(red[tid], red[tid + off]);
    __syncthreads();
  }
  m = red[0]; __syncthreads();
  float s = 0.f;
  for (int q = tid; q < QQ; q += 1024) s += expf(il[q] - m);
  red[tid] = s; __syncthreads();
  for (int off = 512; off > 0; off >>= 1) {
    if (tid < off) red[tid] += red[tid + off];
    __syncthreads();
  }
  s = red[0];
  float inv = 1.0f / s;
  for (int q = tid; q < QQ; q += 1024) ip[q] = expf(il[q] - m) * inv;
}

__global__ void k_prep_B(const float* __restrict__ bl, float* __restrict__ bt) {
  int q = blockIdx.x * blockDim.x + threadIdx.x;
  if (q >= QQ) return;
  const float* row = bl + (size_t)q * SS;
  float m = -1e30f;
  for (int c = 0; c < SS; ++c) m = fmaxf(m, row[c]);
  float s = 0.f;
  for (int c = 0; c < SS; ++c) s += expf(row[c] - m);
  float inv = 1.0f / s;
  for (int c = 0; c < SS; ++c) bt[c * BTS + q] = expf(row[c] - m) * inv;
}

// Row r of A -> column r of A^T[n][k] (bf16, padded with zeros elsewhere)
__global__ void k_prep_A(const float* __restrict__ al, unsigned short* __restrict__ at) {
  int r = blockIdx.x;
  const float* row = al + (size_t)r * QQ;
  __shared__ float red[256];
  int tid = threadIdx.x;
  float m = -1e30f;
  for (int n = tid; n < QQ; n += 256) m = fmaxf(m, row[n]);
  red[tid] = m; __syncthreads();
  for (int off = 128; off > 0; off >>= 1) {
    if (tid < off) red[tid] = fmaxf(red[tid], red[tid + off]);
    __syncthreads();
  }
  m = red[0]; __syncthreads();
  float s = 0.f;
  for (int n = tid; n < QQ; n += 256) s += expf(row[n] - m);
  red[tid] = s; __syncthreads();
  for (int off = 128; off > 0; off >>= 1) {
    if (tid < off) red[tid] += red[tid + off];
    __syncthreads();
  }
  s = red[0];
  float inv = 1.0f / s;
  for (int n = tid; n < QQ; n += 256) at[(size_t)n * KP + r] = f2bf(expf(row[n] - m) * inv);
}

__global__ __launch_bounds__(BLK) void k_hmm(
    const int* __restrict__ seq, const unsigned short* __restrict__ At,
    const float* __restrict__ Bt, const float* __restrict__ ip,
    float* __restrict__ out) {
  __shared__ unsigned short alpha[WR * AST];  // ~34 KB, current alpha in bf16
  __shared__ float spart[NWV][16];
  __shared__ float svec[16];
  __shared__ float invs[16];
  __shared__ int chars[16];
  __shared__ float wred[NWV];

  const int tid = threadIdx.x, wg = blockIdx.x;
  const int lane = tid & 63, wv = tid >> 6;
  const int lrow = lane >> 4, lcol = lane & 15;

  for (int i = tid; i < WR * AST; i += BLK) alpha[i] = 0;
  __syncthreads();

  // ---- prologue: alpha0 = init * E[:,0], normalize, ll = log(s0)
  for (int r = 0; r < WR; ++r) {
    int b = wg * WR + r;
    int c0 = seq[b * TT];
    float part = 0.f;
    for (int q = tid; q < QQ; q += BLK) {
      float v = ip[q] * Bt[c0 * BTS + q];
      part += v;
      alpha[r * AST + q] = f2bf(v);
    }
    for (int off = 32; off > 0; off >>= 1) part += __shfl_down(part, off);
    if (lane == 0) wred[wv] = part;
    __syncthreads();
    if (tid == 0) {
      float s = 0.f;
      for (int w = 0; w < NWV; ++w) s += wred[w];
      svec[r] = s;
    }
    __syncthreads();
  }
  for (int r = 0; r < WR; ++r) {
    float inv = 1.0f / svec[r];
    for (int q = tid; q < QQ; q += BLK)
      alpha[r * AST + q] = f2bf(bf2f(alpha[r * AST + q]) * inv);
  }
  __syncthreads();
  float ll = (tid < WR) ? logf(svec[tid]) : 0.f;

  // per-wave column tiles: tile id = wv + NWV*ti, n0 = 16*tile
  const unsigned short* bp[5];
#pragma unroll
  for (int ti = 0; ti < 5; ++ti) {
    int n = 16 * (wv + NWV * ti) + lcol;
    bp[ti] = At + (size_t)n * KP + 8 * lrow;
  }
  const unsigned short* ap = alpha + lcol * AST + 8 * lrow;

  for (int t = 1; t < TT; ++t) {
    if (tid < WR) chars[tid] = seq[(wg * WR + tid) * TT + t];
    f32x4 acc[5];
#pragma unroll
    for (int ti = 0; ti < 5; ++ti) acc[ti] = (f32x4){0.f, 0.f, 0.f, 0.f};
    for (int ks = 0; ks < KSTEPS; ++ks) {
      bf16x8 af = __builtin_bit_cast(bf16x8, *reinterpret_cast<const u32x4*>(ap + ks * 32));
#pragma unroll
      for (int ti = 0; ti < 5; ++ti) {
        bf16x8 bf = __builtin_bit_cast(bf16x8, *reinterpret_cast<const u32x4*>(bp[ti] + ks * 32));
        acc[ti] = __builtin_amdgcn_mfma_f32_16x16x32_bf16(af, bf, acc[ti], 0, 0, 0);
      }
    }
    __syncthreads();  // bar1: alpha reads done, chars visible

    // epilogue: f = (alpha@A) * e ; per-row partial sums
    float rs[4] = {0.f, 0.f, 0.f, 0.f};
#pragma unroll
    for (int ti = 0; ti < 5; ++ti) {
      int col = 16 * (wv + NWV * ti) + lcol;
#pragma unroll
      for (int i = 0; i < 4; ++i) {
        float e = Bt[chars[4 * lrow + i] * BTS + col];
        float v = acc[ti][i] * e;
        acc[ti][i] = v;
        rs[i] += v;
      }
    }
#pragma unroll
    for (int off = 1; off < 16; off <<= 1) {
#pragma unroll
      for (int i = 0; i < 4; ++i) rs[i] += __shfl_xor(rs[i], off);
    }
    if (lcol == 0) {
#pragma unroll
      for (int i = 0; i < 4; ++i) spart[wv][4 * lrow + i] = rs[i];
    }
    __syncthreads();  // bar2
    if (tid < 16) {
      float s = 0.f;
      for (int w = 0; w < NWV; ++w) s += spart[w][tid];
      invs[tid] = 1.0f / s;
      ll += logf(s);
    }
    __syncthreads();  // bar3: invs ready, safe to overwrite alpha
#pragma unroll
    for (int ti = 0; ti < 5; ++ti) {
      int col = 16 * (wv + NWV * ti) + lcol;
#pragma unroll
      for (int i = 0; i < 4; ++i)
        alpha[(4 * lrow + i) * AST + col] = f2bf(acc[ti][i] * invs[4 * lrow + i]);
    }
    __syncthreads();  // bar4: alpha ready for next step
  }
  if (tid < WR) out[wg * WR + tid] = ll;
}

extern "C" void kernel_launch(void* const* d_in, const int* in_sizes, int n_in,
                              void* d_out, int out_size, void* d_ws, size_t ws_size,
                              hipStream_t stream) {
  const int* seq = (const int*)d_in[0];
  const float* Al = (const float*)d_in[1];
  const float* Bl = (const float*)d_in[2];
  const float* il = (const float*)d_in[3];
  float* out = (float*)d_out;

  char* ws = (char*)d_ws;
  unsigned short* At = (unsigned short*)ws;              // NP*KP bf16 = 2,196,480 B
  size_t off_bt = (size_t)NP * KP * 2;
  float* Bt = (float*)(ws + off_bt);                     // SS*BTS f32 = 108,160 B
  size_t off_ip = off_bt + (size_t)SS * BTS * 4;
  float* ip = (float*)(ws + off_ip);                     // QQ f32
  size_t total = off_ip + 4 * (size_t)((QQ + 3) & ~3);
  int n16 = (int)((total + 15) / 16);

  k_zero<<<(n16 + 255) / 256, 256, 0, stream>>>((u32x4*)ws, n16);
  k_prep_init<<<1, 1024, 0, stream>>>(il, ip);
  k_prep_B<<<(QQ + 255) / 256, 256, 0, stream>>>(Bl, Bt);
  k_prep_A<<<QQ, 256, 0, stream>>>(Al, At);
  k_hmm<<<NB / WR, BLK, 0, stream>>>(seq, At, Bt, ip, out);
}

// Round 2
// 13297.305 us; speedup vs baseline: 2.1326x; 2.1326x over previous
//
#include <hip/hip_runtime.h>
#include <hip/hip_cooperative_groups.h>
#include <math.h>

namespace cg = cooperative_groups;

typedef __bf16 bf16x8 __attribute__((ext_vector_type(8)));
typedef float f32x4 __attribute__((ext_vector_type(4)));
typedef unsigned int u32x4 __attribute__((ext_vector_type(4)));

constexpr int QQ = 1027;   // states
constexpr int SS = 26;     // alphabet
constexpr int TT = 512;    // sequence length
constexpr int NB = 256;    // batch
constexpr int KP = 1056;   // K padded (mult of 32)
constexpr int NP = 1040;   // N padded (65 tiles of 16)
constexpr int BTS = 1040;  // Bt row stride (floats)
constexpr int NSL = 13;    // N slices (5 tiles = 80 cols each)
constexpr int NBB = 8;     // batch blocks
constexpr int MB = 32;     // batch rows per block
constexpr int NWV = 10;    // waves per WG: 2 (M) x 5 (N)
constexpr int CBLK = NWV * 64;
constexpr int KSTEPS = KP / 32;      // 33
constexpr int BUFN = NB * KP;        // bf16 elems per alpha buffer
constexpr int PSN = NB * 16;         // floats per psum buffer

__device__ __forceinline__ unsigned short f2bf(float f) {
  union { float f; unsigned u; } v; v.f = f;
  return (unsigned short)((v.u + 0x7fffu + ((v.u >> 16) & 1u)) >> 16);
}

__global__ void k_zero(u32x4* p, int n) {
  int i = blockIdx.x * blockDim.x + threadIdx.x;
  if (i < n) p[i] = (u32x4){0u, 0u, 0u, 0u};
}

__global__ void k_prep_init(const float* __restrict__ il, float* __restrict__ ip) {
  __shared__ float red[1024];
  int tid = threadIdx.x;
  float m = -1e30f;
  for (int q = tid; q < QQ; q += 1024) m = fmaxf(m, il[q]);
  red[tid] = m; __syncthreads();
  for (int off = 512; off > 0; off >>= 1) {
    if (tid < off) red[tid] = fmaxf(red[tid], red[tid + off]);
    __syncthreads();
  }
  m = red[0]; __syncthreads();
  float s = 0.f;
  for (int q = tid; q < QQ; q += 1024) s += expf(il[q] - m);
  red[tid] = s; __syncthreads();
  for (int off = 512; off > 0; off >>= 1) {
    if (tid < off) red[tid] += red[tid + off];
    __syncthreads();
  }
  s = red[0];
  float inv = 1.0f / s;
  for (int q = tid; q < QQ; q += 1024) ip[q] = expf(il[q] - m) * inv;
}

__global__ void k_prep_B(const float* __restrict__ bl, float* __restrict__ bt) {
  int q = blockIdx.x * blockDim.x + threadIdx.x;
  if (q >= QQ) return;
  const float* row = bl + (size_t)q * SS;
  float m = -1e30f;
  for (int c = 0; c < SS; ++c) m = fmaxf(m, row[c]);
  float s = 0.f;
  for (int c = 0; c < SS; ++c) s += expf(row[c] - m);
  float inv = 1.0f / s;
  for (int c = 0; c < SS; ++c) bt[c * BTS + q] = expf(row[c] - m) * inv;
}

// Row r of A -> column r of A^T[n][k] (bf16)
__global__ void k_prep_A(const float* __restrict__ al, unsigned short* __restrict__ at) {
  int r = blockIdx.x;
  const float* row = al + (size_t)r * QQ;
  __shared__ float red[256];
  int tid = threadIdx.x;
  float m = -1e30f;
  for (int n = tid; n < QQ; n += 256) m = fmaxf(m, row[n]);
  red[tid] = m; __syncthreads();
  for (int off = 128; off > 0; off >>= 1) {
    if (tid < off) red[tid] = fmaxf(red[tid], red[tid + off]);
    __syncthreads();
  }
  m = red[0]; __syncthreads();
  float s = 0.f;
  for (int n = tid; n < QQ; n += 256) s += expf(row[n] - m);
  red[tid] = s; __syncthreads();
  for (int off = 128; off > 0; off >>= 1) {
    if (tid < off) red[tid] += red[tid + off];
    __syncthreads();
  }
  s = red[0];
  float inv = 1.0f / s;
  for (int n = tid; n < QQ; n += 256) at[(size_t)n * KP + r] = f2bf(expf(row[n] - m) * inv);
}

// f0 = init * E[:,0] (unnormalized) into buf0 + per-slice row-sum partials
__global__ void k_init_step(const int* __restrict__ seq, const float* __restrict__ ip,
                            const float* __restrict__ Bt, unsigned short* __restrict__ buf0,
                            float* __restrict__ psum0) {
  int b = blockIdx.x, tid = threadIdx.x;
  __shared__ float sp[16];
  if (tid < 16) sp[tid] = 0.f;
  __syncthreads();
  int c0 = seq[b * TT];
  for (int q = tid; q < NP; q += 256) {
    float v = ip[q] * Bt[c0 * BTS + q];   // ip[q>=QQ]=0, Bt[.,q>=QQ]=0
    buf0[(size_t)b * KP + q] = f2bf(v);
    atomicAdd(&sp[q / 80], v);
  }
  __syncthreads();
  if (tid < 16) psum0[b * 16 + tid] = sp[tid];
}

__global__ __launch_bounds__(CBLK) void k_hmm_coop(
    const int* __restrict__ seq, const unsigned short* __restrict__ At,
    const float* __restrict__ Bt, unsigned short* __restrict__ bufB,
    float* __restrict__ psumB, float* __restrict__ out) {
  cg::grid_group grid = cg::this_grid();
  __shared__ float inv_lds[MB];
  __shared__ int chars[MB];
  __shared__ float spart[MB][5];

  const int tid = threadIdx.x, wg = blockIdx.x;
  const int bb = wg / NSL, sl = wg % NSL;
  const int lane = tid & 63, wv = tid >> 6;
  const int wmt = wv / 5, wc = wv % 5;        // M-tile (0..1), N-tile within slice (0..4)
  const int lrow = lane >> 4, lcol = lane & 15;
  const int n0 = (sl * 5 + wc) * 16;          // global col base of this wave's tile
  const int m0 = bb * MB + wmt * 16;          // global row base of this wave's tile

  const unsigned short* bp = At + (size_t)(n0 + lcol) * KP + 8 * lrow;
  float ll = 0.f;

  for (int t = 1; t < TT; ++t) {
    const int rd = (t - 1) % 3, wri = t % 3;
    const unsigned short* abuf = bufB + (size_t)rd * BUFN;
    unsigned short* wbuf = bufB + (size_t)wri * BUFN;

    if (tid < MB) {
      int row = bb * MB + tid;
      const float* pp = psumB + (size_t)rd * PSN + row * 16;
      float s = 0.f;
#pragma unroll
      for (int j = 0; j < 16; ++j) s += pp[j];
      ll += logf(s);
      inv_lds[tid] = 1.0f / s;
      chars[tid] = seq[row * TT + t];
    }
    __syncthreads();

    const unsigned short* ap = abuf + (size_t)(m0 + lcol) * KP + 8 * lrow;
    f32x4 acc = (f32x4){0.f, 0.f, 0.f, 0.f};
#pragma unroll 3
    for (int ks = 0; ks < KSTEPS; ++ks) {
      bf16x8 af = __builtin_bit_cast(bf16x8, *reinterpret_cast<const u32x4*>(ap + ks * 32));
      bf16x8 bf = __builtin_bit_cast(bf16x8, *reinterpret_cast<const u32x4*>(bp + ks * 32));
      acc = __builtin_amdgcn_mfma_f32_16x16x32_bf16(af, bf, acc, 0, 0, 0);
    }

    float rs[4];
#pragma unroll
    for (int i = 0; i < 4; ++i) {
      int r = wmt * 16 + 4 * lrow + i;        // row within batch block (0..31)
      float e = Bt[chars[r] * BTS + n0 + lcol];
      float v = acc[i] * e * inv_lds[r];
      acc[i] = v;
      rs[i] = v;
    }
#pragma unroll
    for (int off = 1; off < 16; off <<= 1) {
#pragma unroll
      for (int i = 0; i < 4; ++i) rs[i] += __shfl_xor(rs[i], off);
    }
    if (lcol == 0) {
#pragma unroll
      for (int i = 0; i < 4; ++i) spart[wmt * 16 + 4 * lrow + i][wc] = rs[i];
    }
#pragma unroll
    for (int i = 0; i < 4; ++i) {
      int g = bb * MB + wmt * 16 + 4 * lrow + i;
      wbuf[(size_t)g * KP + n0 + lcol] = f2bf(acc[i]);
    }
    __syncthreads();
    if (tid < MB) {
      float s5 = spart[tid][0] + spart[tid][1] + spart[tid][2] +
                 spart[tid][3] + spart[tid][4];
      psumB[(size_t)wri * PSN + (bb * MB + tid) * 16 + sl] = s5;
    }
    grid.sync();
  }

  if (sl == 0 && tid < MB) {
    int row = bb * MB + tid;
    const float* pp = psumB + (size_t)((TT - 1) % 3) * PSN + row * 16;
    float s = 0.f;
#pragma unroll
    for (int j = 0; j < 16; ++j) s += pp[j];
    out[row] = ll + logf(s);
  }
}

extern "C" void kernel_launch(void* const* d_in, const int* in_sizes, int n_in,
                              void* d_out, int out_size, void* d_ws, size_t ws_size,
                              hipStream_t stream) {
  const int* seq = (const int*)d_in[0];
  const float* Al = (const float*)d_in[1];
  const float* Bl = (const float*)d_in[2];
  const float* il = (const float*)d_in[3];
  float* out = (float*)d_out;

  char* ws = (char*)d_ws;
  unsigned short* At = (unsigned short*)ws;               // 1040*1056*2 = 2,196,480
  size_t off_bt = (size_t)NP * KP * 2;
  float* Bt = (float*)(ws + off_bt);                      // 26*1040*4 = 108,160
  size_t off_ip = off_bt + (size_t)SS * BTS * 4;
  float* ip = (float*)(ws + off_ip);                      // 1040*4 = 4,160
  size_t off_buf = off_ip + (size_t)NP * 4;
  unsigned short* bufB = (unsigned short*)(ws + off_buf); // 3*256*1056*2 = 1,622,016
  size_t off_ps = off_buf + (size_t)3 * BUFN * 2;
  float* psumB = (float*)(ws + off_ps);                   // 3*256*16*4 = 49,152
  size_t total = off_ps + (size_t)3 * PSN * 4;
  int n16 = (int)((total + 15) / 16);

  k_zero<<<(n16 + 255) / 256, 256, 0, stream>>>((u32x4*)ws, n16);
  k_prep_init<<<1, 1024, 0, stream>>>(il, ip);
  k_prep_B<<<(QQ + 255) / 256, 256, 0, stream>>>(Bl, Bt);
  k_prep_A<<<QQ, 256, 0, stream>>>(Al, At);
  k_init_step<<<NB, 256, 0, stream>>>(seq, ip, Bt, bufB, psumB);

  void* args[] = {(void*)&seq, (void*)&At, (void*)&Bt, (void*)&bufB,
                  (void*)&psumB, (void*)&out};
  hipLaunchCooperativeKernel((void*)k_hmm_coop, dim3(NBB * NSL), dim3(CBLK),
                             args, 0, stream);
}

// Round 3
// 8961.808 us; speedup vs baseline: 3.1644x; 1.4838x over previous
//
#include <hip/hip_runtime.h>
#include <hip/hip_cooperative_groups.h>
#include <math.h>

typedef __bf16 bf16x8 __attribute__((ext_vector_type(8)));
typedef float f32x4 __attribute__((ext_vector_type(4)));
typedef unsigned int u32x4 __attribute__((ext_vector_type(4)));

constexpr int QQ = 1027;   // states
constexpr int SS = 26;     // alphabet
constexpr int TT = 512;    // sequence length
constexpr int NB = 256;    // batch
constexpr int KP = 1056;   // K padded (mult of 32)
constexpr int NP = 1040;   // N padded (65 tiles of 16)
constexpr int BTS = 1040;  // Bt row stride (floats)
constexpr int NSL = 13;    // N slices (5 tiles = 80 cols each)
constexpr int NBB = 8;     // batch blocks
constexpr int MB = 32;     // batch rows per block
constexpr int NWV = 10;    // waves per WG: 2 (M) x 5 (N)
constexpr int CBLK = NWV * 64;
constexpr int KSTEPS = KP / 32;      // 33
constexpr int BUFN = NB * KP;        // bf16 elems per alpha buffer
constexpr int PSN = NB * 16;         // floats per psum buffer

__device__ __forceinline__ unsigned short f2bf(float f) {
  union { float f; unsigned u; } v; v.f = f;
  return (unsigned short)((v.u + 0x7fffu + ((v.u >> 16) & 1u)) >> 16);
}

__global__ void k_zero(u32x4* p, int n) {
  int i = blockIdx.x * blockDim.x + threadIdx.x;
  if (i < n) p[i] = (u32x4){0u, 0u, 0u, 0u};
}

__global__ void k_prep_init(const float* __restrict__ il, float* __restrict__ ip) {
  __shared__ float red[1024];
  int tid = threadIdx.x;
  float m = -1e30f;
  for (int q = tid; q < QQ; q += 1024) m = fmaxf(m, il[q]);
  red[tid] = m; __syncthreads();
  for (int off = 512; off > 0; off >>= 1) {
    if (tid < off) red[tid] = fmaxf(red[tid], red[tid + off]);
    __syncthreads();
  }
  m = red[0]; __syncthreads();
  float s = 0.f;
  for (int q = tid; q < QQ; q += 1024) s += expf(il[q] - m);
  red[tid] = s; __syncthreads();
  for (int off = 512; off > 0; off >>= 1) {
    if (tid < off) red[tid] += red[tid + off];
    __syncthreads();
  }
  s = red[0];
  float inv = 1.0f / s;
  for (int q = tid; q < QQ; q += 1024) ip[q] = expf(il[q] - m) * inv;
}

__global__ void k_prep_B(const float* __restrict__ bl, float* __restrict__ bt) {
  int q = blockIdx.x * blockDim.x + threadIdx.x;
  if (q >= QQ) return;
  const float* row = bl + (size_t)q * SS;
  float m = -1e30f;
  for (int c = 0; c < SS; ++c) m = fmaxf(m, row[c]);
  float s = 0.f;
  for (int c = 0; c < SS; ++c) s += expf(row[c] - m);
  float inv = 1.0f / s;
  for (int c = 0; c < SS; ++c) bt[c * BTS + q] = expf(row[c] - m) * inv;
}

// Row r of A -> column r of A^T[n][k] (bf16)
__global__ void k_prep_A(const float* __restrict__ al, unsigned short* __restrict__ at) {
  int r = blockIdx.x;
  const float* row = al + (size_t)r * QQ;
  __shared__ float red[256];
  int tid = threadIdx.x;
  float m = -1e30f;
  for (int n = tid; n < QQ; n += 256) m = fmaxf(m, row[n]);
  red[tid] = m; __syncthreads();
  for (int off = 128; off > 0; off >>= 1) {
    if (tid < off) red[tid] = fmaxf(red[tid], red[tid + off]);
    __syncthreads();
  }
  m = red[0]; __syncthreads();
  float s = 0.f;
  for (int n = tid; n < QQ; n += 256) s += expf(row[n] - m);
  red[tid] = s; __syncthreads();
  for (int off = 128; off > 0; off >>= 1) {
    if (tid < off) red[tid] += red[tid + off];
    __syncthreads();
  }
  s = red[0];
  float inv = 1.0f / s;
  for (int n = tid; n < QQ; n += 256) at[(size_t)n * KP + r] = f2bf(expf(row[n] - m) * inv);
}

// f0 = init * E[:,0] (unnormalized) into buf0 + per-slice row-sum partials
__global__ void k_init_step(const int* __restrict__ seq, const float* __restrict__ ip,
                            const float* __restrict__ Bt, unsigned short* __restrict__ buf0,
                            float* __restrict__ psum0) {
  int b = blockIdx.x, tid = threadIdx.x;
  __shared__ float sp[16];
  if (tid < 16) sp[tid] = 0.f;
  __syncthreads();
  int c0 = seq[b * TT];
  for (int q = tid; q < NP; q += 256) {
    float v = ip[q] * Bt[c0 * BTS + q];   // ip[q>=QQ]=0, Bt[.,q>=QQ]=0
    buf0[(size_t)b * KP + q] = f2bf(v);
    atomicAdd(&sp[q / 80], v);
  }
  __syncthreads();
  if (tid < 16) psum0[b * 16 + tid] = sp[tid];
}

__global__ __launch_bounds__(CBLK) void k_hmm_coop(
    const int* __restrict__ seq, const unsigned short* __restrict__ At,
    const float* __restrict__ Bt, unsigned short* __restrict__ bufB,
    float* __restrict__ psumB, unsigned* __restrict__ barc,
    float* __restrict__ out) {
  __shared__ float inv_lds[MB];
  __shared__ int chars[MB];
  __shared__ float spart[MB][5];

  const int tid = threadIdx.x, wg = blockIdx.x;
  // bb = wg % 8: under round-robin blockIdx->XCD, the 13 WGs of one batch
  // block land on one XCD (perf heuristic only; correctness via agent fences)
  const int bb = wg % NBB, sl = wg / NBB;
  const int lane = tid & 63, wv = tid >> 6;
  const int wmt = wv / 5, wc = wv % 5;        // M-tile (0..1), N-tile within slice
  const int lrow = lane >> 4, lcol = lane & 15;
  const int n0 = (sl * 5 + wc) * 16;          // global col base of this wave's tile
  const int m0 = bb * MB + wmt * 16;          // global row base of this wave's tile

  const unsigned short* bp = At + (size_t)(n0 + lcol) * KP + 8 * lrow;
  unsigned* bar = barc + bb * 16;             // 64B-padded counter per batch block
  float ll = 0.f;

  for (int t = 1; t < TT; ++t) {
    const int rd = (t - 1) % 3, wri = t % 3;
    const unsigned short* abuf = bufB + (size_t)rd * BUFN;
    unsigned short* wbuf = bufB + (size_t)wri * BUFN;

    if (tid < MB) {
      int row = bb * MB + tid;
      const float* pp = psumB + (size_t)rd * PSN + row * 16;
      float s = 0.f;
#pragma unroll
      for (int j = 0; j < 16; ++j) s += pp[j];
      ll += logf(s);
      inv_lds[tid] = 1.0f / s;
      chars[tid] = seq[row * TT + t];
    }
    __syncthreads();  // bar A: inv/chars visible

    const unsigned short* ap = abuf + (size_t)(m0 + lcol) * KP + 8 * lrow;
    f32x4 acc = (f32x4){0.f, 0.f, 0.f, 0.f};
#pragma unroll 3
    for (int ks = 0; ks < KSTEPS; ++ks) {
      bf16x8 af = __builtin_bit_cast(bf16x8, *reinterpret_cast<const u32x4*>(ap + ks * 32));
      bf16x8 bf = __builtin_bit_cast(bf16x8, *reinterpret_cast<const u32x4*>(bp + ks * 32));
      acc = __builtin_amdgcn_mfma_f32_16x16x32_bf16(af, bf, acc, 0, 0, 0);
    }

    float rs[4];
#pragma unroll
    for (int i = 0; i < 4; ++i) {
      int r = wmt * 16 + 4 * lrow + i;        // row within batch block
      float e = Bt[chars[r] * BTS + n0 + lcol];
      float v = acc[i] * e * inv_lds[r];
      acc[i] = v;
      rs[i] = v;
    }
#pragma unroll
    for (int off = 1; off < 16; off <<= 1) {
#pragma unroll
      for (int i = 0; i < 4; ++i) rs[i] += __shfl_xor(rs[i], off);
    }
    if (lcol == 0) {
#pragma unroll
      for (int i = 0; i < 4; ++i) spart[wmt * 16 + 4 * lrow + i][wc] = rs[i];
    }
#pragma unroll
    for (int i = 0; i < 4; ++i) {
      int g = bb * MB + wmt * 16 + 4 * lrow + i;
      wbuf[(size_t)g * KP + n0 + lcol] = f2bf(acc[i]);
    }
    __syncthreads();  // bar B: spart + wbuf stores drained
    if (tid < MB) {
      float s5 = spart[tid][0] + spart[tid][1] + spart[tid][2] +
                 spart[tid][3] + spart[tid][4];
      psumB[(size_t)wri * PSN + (bb * MB + tid) * 16 + sl] = s5;
    }
    __syncthreads();  // bar C: psum stores drained to L2

    // --- per-batch-block barrier (monotonic counter, 13 arrivals per step)
    if (tid == 0) {
      __threadfence();                       // agent release: publish wbuf+psum
      atomicAdd(bar, 1u);
      const unsigned target = (unsigned)NSL * (unsigned)t;
      while (__hip_atomic_load(bar, __ATOMIC_RELAXED, __HIP_MEMORY_SCOPE_AGENT) < target)
        __builtin_amdgcn_s_sleep(1);
      __threadfence();                       // agent acquire: invalidate stale
    }
    __syncthreads();  // bar D: release whole WG into next step
  }

  if (sl == 0 && tid < MB) {
    int row = bb * MB + tid;
    const float* pp = psumB + (size_t)((TT - 1) % 3) * PSN + row * 16;
    float s = 0.f;
#pragma unroll
    for (int j = 0; j < 16; ++j) s += pp[j];
    out[row] = ll + logf(s);
  }
}

extern "C" void kernel_launch(void* const* d_in, const int* in_sizes, int n_in,
                              void* d_out, int out_size, void* d_ws, size_t ws_size,
                              hipStream_t stream) {
  const int* seq = (const int*)d_in[0];
  const float* Al = (const float*)d_in[1];
  const float* Bl = (const float*)d_in[2];
  const float* il = (const float*)d_in[3];
  float* out = (float*)d_out;

  char* ws = (char*)d_ws;
  unsigned short* At = (unsigned short*)ws;               // 1040*1056*2 = 2,196,480
  size_t off_bt = (size_t)NP * KP * 2;
  float* Bt = (float*)(ws + off_bt);                      // 26*1040*4 = 108,160
  size_t off_ip = off_bt + (size_t)SS * BTS * 4;
  float* ip = (float*)(ws + off_ip);                      // 1040*4
  size_t off_buf = off_ip + (size_t)NP * 4;
  unsigned short* bufB = (unsigned short*)(ws + off_buf); // 3*256*1056*2 = 1,622,016
  size_t off_ps = off_buf + (size_t)3 * BUFN * 2;
  float* psumB = (float*)(ws + off_ps);                   // 3*256*16*4 = 49,152
  size_t off_bar = off_ps + (size_t)3 * PSN * 4;
  unsigned* barc = (unsigned*)(ws + off_bar);             // 8 counters, 64B apart
  size_t total = off_bar + (size_t)NBB * 64;
  int n16 = (int)((total + 15) / 16);

  k_zero<<<(n16 + 255) / 256, 256, 0, stream>>>((u32x4*)ws, n16);
  k_prep_init<<<1, 1024, 0, stream>>>(il, ip);
  k_prep_B<<<(QQ + 255) / 256, 256, 0, stream>>>(Bl, Bt);
  k_prep_A<<<QQ, 256, 0, stream>>>(Al, At);
  k_init_step<<<NB, 256, 0, stream>>>(seq, ip, Bt, bufB, psumB);

  void* args[] = {(void*)&seq, (void*)&At, (void*)&Bt, (void*)&bufB,
                  (void*)&psumB, (void*)&barc, (void*)&out};
  hipLaunchCooperativeKernel((void*)k_hmm_coop, dim3(NBB * NSL), dim3(CBLK),
                             args, 0, stream);
}

// Round 4
// 4941.208 us; speedup vs baseline: 5.7392x; 1.8137x over previous
//
#include <hip/hip_runtime.h>
#include <math.h>

typedef __bf16 bf16x8 __attribute__((ext_vector_type(8)));
typedef float f32x4 __attribute__((ext_vector_type(4)));
typedef unsigned int u32x4 __attribute__((ext_vector_type(4)));
typedef unsigned long long u64;

constexpr int QQ = 1027;   // states
constexpr int SS = 26;     // alphabet
constexpr int TT = 512;    // sequence length
constexpr int NB = 256;    // batch
constexpr int KP = 1056;   // K padded (mult of 32)
constexpr int NP = 1040;   // N padded (65 tiles of 16)
constexpr int BTS = 1040;  // Bt row stride (floats)
constexpr int NSL = 13;    // N slices (5 tiles = 80 cols each)
constexpr int NBB = 8;     // batch blocks
constexpr int MB = 32;     // batch rows per block
constexpr int NWV = 10;    // waves per WG: 2 (M) x 5 (N)
constexpr int CBLK = NWV * 64;
constexpr int KSTEPS = KP / 32;      // 33
constexpr int BUFN = NB * KP;        // bf16 elems per alpha buffer
constexpr int PSN = NB * 16;         // floats per psum buffer
constexpr int RQ = KP / 4;           // 264 u64 per alpha row
constexpr int LQ = RQ + 2;           // 266 u64 LDS row stride (2128B: 2-way banks, free)
constexpr int TOTQ = MB * RQ;        // 8448 u64 per batch-block alpha
constexpr int NFULL = TOTQ - 13 * CBLK;  // 128 threads do a 14th element

__device__ __forceinline__ unsigned short f2bf(float f) {
  union { float f; unsigned u; } v; v.f = f;
  return (unsigned short)((v.u + 0x7fffu + ((v.u >> 16) & 1u)) >> 16);
}

__device__ __forceinline__ u64 ald8(const u64* p) {
  return __hip_atomic_load((u64*)p, __ATOMIC_RELAXED, __HIP_MEMORY_SCOPE_AGENT);
}
__device__ __forceinline__ void ast2(unsigned short* p, unsigned short v) {
  __hip_atomic_store(p, v, __ATOMIC_RELAXED, __HIP_MEMORY_SCOPE_AGENT);
}
__device__ __forceinline__ void ast4(float* p, float v) {
  __hip_atomic_store(p, v, __ATOMIC_RELAXED, __HIP_MEMORY_SCOPE_AGENT);
}

__global__ void k_zero(u32x4* p, int n) {
  int i = blockIdx.x * blockDim.x + threadIdx.x;
  if (i < n) p[i] = (u32x4){0u, 0u, 0u, 0u};
}

__global__ void k_prep_init(const float* __restrict__ il, float* __restrict__ ip) {
  __shared__ float red[1024];
  int tid = threadIdx.x;
  float m = -1e30f;
  for (int q = tid; q < QQ; q += 1024) m = fmaxf(m, il[q]);
  red[tid] = m; __syncthreads();
  for (int off = 512; off > 0; off >>= 1) {
    if (tid < off) red[tid] = fmaxf(red[tid], red[tid + off]);
    __syncthreads();
  }
  m = red[0]; __syncthreads();
  float s = 0.f;
  for (int q = tid; q < QQ; q += 1024) s += expf(il[q] - m);
  red[tid] = s; __syncthreads();
  for (int off = 512; off > 0; off >>= 1) {
    if (tid < off) red[tid] += red[tid + off];
    __syncthreads();
  }
  s = red[0];
  float inv = 1.0f / s;
  for (int q = tid; q < QQ; q += 1024) ip[q] = expf(il[q] - m) * inv;
}

__global__ void k_prep_B(const float* __restrict__ bl, float* __restrict__ bt) {
  int q = blockIdx.x * blockDim.x + threadIdx.x;
  if (q >= QQ) return;
  const float* row = bl + (size_t)q * SS;
  float m = -1e30f;
  for (int c = 0; c < SS; ++c) m = fmaxf(m, row[c]);
  float s = 0.f;
  for (int c = 0; c < SS; ++c) s += expf(row[c] - m);
  float inv = 1.0f / s;
  for (int c = 0; c < SS; ++c) bt[c * BTS + q] = expf(row[c] - m) * inv;
}

// Row r of A -> column r of A^T[n][k] (bf16)
__global__ void k_prep_A(const float* __restrict__ al, unsigned short* __restrict__ at) {
  int r = blockIdx.x;
  const float* row = al + (size_t)r * QQ;
  __shared__ float red[256];
  int tid = threadIdx.x;
  float m = -1e30f;
  for (int n = tid; n < QQ; n += 256) m = fmaxf(m, row[n]);
  red[tid] = m; __syncthreads();
  for (int off = 128; off > 0; off >>= 1) {
    if (tid < off) red[tid] = fmaxf(red[tid], red[tid + off]);
    __syncthreads();
  }
  m = red[0]; __syncthreads();
  float s = 0.f;
  for (int n = tid; n < QQ; n += 256) s += expf(row[n] - m);
  red[tid] = s; __syncthreads();
  for (int off = 128; off > 0; off >>= 1) {
    if (tid < off) red[tid] += red[tid + off];
    __syncthreads();
  }
  s = red[0];
  float inv = 1.0f / s;
  for (int n = tid; n < QQ; n += 256) at[(size_t)n * KP + r] = f2bf(expf(row[n] - m) * inv);
}

// f0 = init * E[:,0] (unnormalized) into buf0 + per-slice row-sum partials
__global__ void k_init_step(const int* __restrict__ seq, const float* __restrict__ ip,
                            const float* __restrict__ Bt, unsigned short* __restrict__ buf0,
                            float* __restrict__ psum0) {
  int b = blockIdx.x, tid = threadIdx.x;
  __shared__ float sp[16];
  if (tid < 16) sp[tid] = 0.f;
  __syncthreads();
  int c0 = seq[b * TT];
  for (int q = tid; q < NP; q += 256) {
    float v = ip[q] * Bt[c0 * BTS + q];   // ip[q>=QQ]=0, Bt[.,q>=QQ]=0
    buf0[(size_t)b * KP + q] = f2bf(v);
    atomicAdd(&sp[q / 80], v);
  }
  __syncthreads();
  if (tid < 16) psum0[b * 16 + tid] = sp[tid];
}

__global__ __launch_bounds__(CBLK) void k_hmm_coop(
    const int* __restrict__ seq, const unsigned short* __restrict__ At,
    const float* __restrict__ Bt, unsigned short* __restrict__ bufB,
    float* __restrict__ psumB, unsigned* __restrict__ barc,
    float* __restrict__ out) {
  __shared__ u64 aldsq[MB * LQ];          // 68,096 B: this block's alpha (bf16)
  __shared__ float inv_lds[MB];
  __shared__ int chars[MB];
  __shared__ float spart[MB][5];

  const int tid = threadIdx.x, wg = blockIdx.x;
  const int bb = wg % NBB, sl = wg / NBB; // 13 WGs per batch block
  const int lane = tid & 63, wv = tid >> 6;
  const int wmt = wv / 5, wc = wv % 5;    // M-tile (0..1), N-tile within slice
  const int lrow = lane >> 4, lcol = lane & 15;
  const int n0 = (sl * 5 + wc) * 16;      // global col base of this wave's tile

  const unsigned short* alds = (const unsigned short*)aldsq;  // row stride LQ*4=1064
  const unsigned short* bp = At + (size_t)(n0 + lcol) * KP + 8 * lrow;
  unsigned* bar = barc + bb * 16;
  float ll = 0.f;

  for (int t = 1; t < TT; ++t) {
    const int rd = (t - 1) % 3, wri = t % 3;
    const unsigned short* abuf = bufB + (size_t)rd * BUFN;
    unsigned short* wbuf = bufB + (size_t)wri * BUFN;

    // --- A: issue coherent loads (alpha block + psums), max MLP
    const u64* asrc = (const u64*)abuf + (size_t)bb * MB * RQ + tid;
    u64 av[13], av13 = 0;
#pragma unroll
    for (int j = 0; j < 13; ++j) av[j] = ald8(asrc + j * CBLK);
    if (tid < NFULL) av13 = ald8(asrc + 13 * CBLK);
    u64 pq[8]; int ch = 0;
    if (tid < MB) {
      const u64* pp = (const u64*)(psumB + (size_t)rd * PSN + (bb * MB + tid) * 16);
#pragma unroll
      for (int j = 0; j < 8; ++j) pq[j] = ald8(pp + j);
      ch = seq[(bb * MB + tid) * TT + t];
    }

    // --- B: stage alpha into LDS (padded row stride)
#pragma unroll
    for (int j = 0; j < 13; ++j) {
      int g = tid + j * CBLK;
      int r = g / RQ;
      aldsq[r * LQ + (g - r * RQ)] = av[j];
    }
    if (tid < NFULL) {
      int g = tid + 13 * CBLK;
      int r = g / RQ;
      aldsq[r * LQ + (g - r * RQ)] = av13;
    }
    // --- C: scales + log-lik update
    if (tid < MB) {
      float s = 0.f;
#pragma unroll
      for (int j = 0; j < 8; ++j) {
        union { u64 q; float f[2]; } uu; uu.q = pq[j];
        s += uu.f[0] + uu.f[1];
      }
      ll += logf(s);
      inv_lds[tid] = 1.0f / s;
      chars[tid] = ch;
    }
    __syncthreads();  // LDS alpha + inv/chars ready

    // --- E: MFMA, A-frag from LDS, B-frag from L2-resident At
    const unsigned short* ap = alds + (size_t)(wmt * 16 + lcol) * (LQ * 4) + 8 * lrow;
    f32x4 acc = (f32x4){0.f, 0.f, 0.f, 0.f};
#pragma unroll
    for (int ks = 0; ks < KSTEPS; ++ks) {
      bf16x8 af = __builtin_bit_cast(bf16x8, *reinterpret_cast<const u32x4*>(ap + ks * 32));
      bf16x8 bfv = __builtin_bit_cast(bf16x8, *reinterpret_cast<const u32x4*>(bp + ks * 32));
      acc = __builtin_amdgcn_mfma_f32_16x16x32_bf16(af, bfv, acc, 0, 0, 0);
    }

    // --- F: epilogue f = g*e/s_prev; coherent alpha store; row partial sums
    float rs[4];
#pragma unroll
    for (int i = 0; i < 4; ++i) {
      int r = wmt * 16 + 4 * lrow + i;
      int g = bb * MB + r;
      float e = Bt[chars[r] * BTS + n0 + lcol];
      float v = acc[i] * e * inv_lds[r];
      ast2(wbuf + (size_t)g * KP + n0 + lcol, f2bf(v));
      rs[i] = v;
    }
#pragma unroll
    for (int off = 1; off < 16; off <<= 1) {
#pragma unroll
      for (int i = 0; i < 4; ++i) rs[i] += __shfl_xor(rs[i], off);
    }
    if (lcol == 0) {
#pragma unroll
      for (int i = 0; i < 4; ++i) spart[wmt * 16 + 4 * lrow + i][wc] = rs[i];
    }
    __syncthreads();  // spart ready; all waves' alpha stores drained here

    if (tid < MB) {
      float s5 = spart[tid][0] + spart[tid][1] + spart[tid][2] +
                 spart[tid][3] + spart[tid][4];
      ast4(psumB + (size_t)wri * PSN + (bb * MB + tid) * 16 + sl, s5);
    }
    // --- barrier: 13 arrivals per batch block, monotonic counter at L3
    if (tid == 0) {
      asm volatile("s_waitcnt vmcnt(0)" ::: "memory");  // psum/alpha (wave0) acked
      __hip_atomic_fetch_add(bar, 1u, __ATOMIC_RELAXED, __HIP_MEMORY_SCOPE_AGENT);
      const unsigned target = (unsigned)NSL * (unsigned)t;
      while (__hip_atomic_load(bar, __ATOMIC_RELAXED, __HIP_MEMORY_SCOPE_AGENT) < target)
        __builtin_amdgcn_s_sleep(1);
    }
    __syncthreads();
    asm volatile("" ::: "memory");
  }

  if (sl == 0 && tid < MB) {
    const u64* pp = (const u64*)(psumB + (size_t)((TT - 1) % 3) * PSN + (bb * MB + tid) * 16);
    float s = 0.f;
#pragma unroll
    for (int j = 0; j < 8; ++j) {
      union { u64 q; float f[2]; } uu; uu.q = ald8(pp + j);
      s += uu.f[0] + uu.f[1];
    }
    out[bb * MB + tid] = ll + logf(s);
  }
}

extern "C" void kernel_launch(void* const* d_in, const int* in_sizes, int n_in,
                              void* d_out, int out_size, void* d_ws, size_t ws_size,
                              hipStream_t stream) {
  const int* seq = (const int*)d_in[0];
  const float* Al = (const float*)d_in[1];
  const float* Bl = (const float*)d_in[2];
  const float* il = (const float*)d_in[3];
  float* out = (float*)d_out;

  char* ws = (char*)d_ws;
  unsigned short* At = (unsigned short*)ws;               // 1040*1056*2 = 2,196,480
  size_t off_bt = (size_t)NP * KP * 2;
  float* Bt = (float*)(ws + off_bt);                      // 26*1040*4 = 108,160
  size_t off_ip = off_bt + (size_t)SS * BTS * 4;
  float* ip = (float*)(ws + off_ip);                      // 1040*4
  size_t off_buf = off_ip + (size_t)NP * 4;
  unsigned short* bufB = (unsigned short*)(ws + off_buf); // 3*256*1056*2 = 1,622,016
  size_t off_ps = off_buf + (size_t)3 * BUFN * 2;
  float* psumB = (float*)(ws + off_ps);                   // 3*256*16*4 = 49,152
  size_t off_bar = off_ps + (size_t)3 * PSN * 4;
  unsigned* barc = (unsigned*)(ws + off_bar);             // 8 counters, 64B apart
  size_t total = off_bar + (size_t)NBB * 64;
  int n16 = (int)((total + 15) / 16);

  k_zero<<<(n16 + 255) / 256, 256, 0, stream>>>((u32x4*)ws, n16);
  k_prep_init<<<1, 1024, 0, stream>>>(il, ip);
  k_prep_B<<<(QQ + 255) / 256, 256, 0, stream>>>(Bl, Bt);
  k_prep_A<<<QQ, 256, 0, stream>>>(Al, At);
  k_init_step<<<NB, 256, 0, stream>>>(seq, ip, Bt, bufB, psumB);

  void* args[] = {(void*)&seq, (void*)&At, (void*)&Bt, (void*)&bufB,
                  (void*)&psumB, (void*)&barc, (void*)&out};
  hipLaunchCooperativeKernel((void*)k_hmm_coop, dim3(NBB * NSL), dim3(CBLK),
                             args, 0, stream);
}

// Round 5
// 1967.806 us; speedup vs baseline: 14.4112x; 2.5110x over previous
//
#include <hip/hip_runtime.h>
#include <math.h>

typedef __bf16 bf16x8 __attribute__((ext_vector_type(8)));
typedef float f32x4 __attribute__((ext_vector_type(4)));
typedef unsigned int u32x4 __attribute__((ext_vector_type(4)));
typedef unsigned long long u64;

constexpr int QQ = 1027;   // states
constexpr int SS = 26;     // alphabet
constexpr int TT = 512;    // sequence length
constexpr int NB = 256;    // batch
constexpr int KP = 1056;   // K padded (mult of 32)
constexpr int NP = 1040;   // N padded (65 tiles of 16)
constexpr int BTS = 1040;  // Bt row stride (floats)
constexpr int NSL = 13;    // N slices (5 tiles = 80 cols each)
constexpr int NBB = 16;    // batch blocks
constexpr int MB = 16;     // batch rows per block
constexpr int NWV = 5;     // waves per WG (1 N-tile each)
constexpr int CBLK = NWV * 64;       // 320
constexpr int KSTEPS = KP / 32;      // 33
constexpr int BUFN = NB * KP;        // bf16 elems per alpha buffer
constexpr int PSN = NB * 16;         // floats per psum buffer
constexpr int RQ = KP / 4;           // 264 u64 per alpha row
constexpr int LQ = RQ + 2;           // 266 u64 LDS row stride (2128B)
constexpr int TOTQ = MB * RQ;        // 4224 u64 per batch-block alpha
constexpr int NLD = TOTQ / CBLK;     // 13 full loads per thread
constexpr int NREM = TOTQ - NLD * CBLK;  // 64 threads do one more

__device__ __forceinline__ unsigned short f2bf(float f) {
  union { float f; unsigned u; } v; v.f = f;
  return (unsigned short)((v.u + 0x7fffu + ((v.u >> 16) & 1u)) >> 16);
}

__device__ __forceinline__ u64 ald8(const u64* p) {
  return __hip_atomic_load((u64*)p, __ATOMIC_RELAXED, __HIP_MEMORY_SCOPE_AGENT);
}
__device__ __forceinline__ void ast8(u64* p, u64 v) {
  __hip_atomic_store(p, v, __ATOMIC_RELAXED, __HIP_MEMORY_SCOPE_AGENT);
}
__device__ __forceinline__ void ast4(float* p, float v) {
  __hip_atomic_store(p, v, __ATOMIC_RELAXED, __HIP_MEMORY_SCOPE_AGENT);
}

__global__ void k_zero(u32x4* p, int n) {
  int i = blockIdx.x * blockDim.x + threadIdx.x;
  if (i < n) p[i] = (u32x4){0u, 0u, 0u, 0u};
}

__global__ void k_prep_init(const float* __restrict__ il, float* __restrict__ ip) {
  __shared__ float red[1024];
  int tid = threadIdx.x;
  float m = -1e30f;
  for (int q = tid; q < QQ; q += 1024) m = fmaxf(m, il[q]);
  red[tid] = m; __syncthreads();
  for (int off = 512; off > 0; off >>= 1) {
    if (tid < off) red[tid] = fmaxf(red[tid], red[tid + off]);
    __syncthreads();
  }
  m = red[0]; __syncthreads();
  float s = 0.f;
  for (int q = tid; q < QQ; q += 1024) s += expf(il[q] - m);
  red[tid] = s; __syncthreads();
  for (int off = 512; off > 0; off >>= 1) {
    if (tid < off) red[tid] += red[tid + off];
    __syncthreads();
  }
  s = red[0];
  float inv = 1.0f / s;
  for (int q = tid; q < QQ; q += 1024) ip[q] = expf(il[q] - m) * inv;
}

__global__ void k_prep_B(const float* __restrict__ bl, float* __restrict__ bt) {
  int q = blockIdx.x * blockDim.x + threadIdx.x;
  if (q >= QQ) return;
  const float* row = bl + (size_t)q * SS;
  float m = -1e30f;
  for (int c = 0; c < SS; ++c) m = fmaxf(m, row[c]);
  float s = 0.f;
  for (int c = 0; c < SS; ++c) s += expf(row[c] - m);
  float inv = 1.0f / s;
  for (int c = 0; c < SS; ++c) bt[c * BTS + q] = expf(row[c] - m) * inv;
}

// Row r of A -> column r of A^T[n][k] (bf16)
__global__ void k_prep_A(const float* __restrict__ al, unsigned short* __restrict__ at) {
  int r = blockIdx.x;
  const float* row = al + (size_t)r * QQ;
  __shared__ float red[256];
  int tid = threadIdx.x;
  float m = -1e30f;
  for (int n = tid; n < QQ; n += 256) m = fmaxf(m, row[n]);
  red[tid] = m; __syncthreads();
  for (int off = 128; off > 0; off >>= 1) {
    if (tid < off) red[tid] = fmaxf(red[tid], red[tid + off]);
    __syncthreads();
  }
  m = red[0]; __syncthreads();
  float s = 0.f;
  for (int n = tid; n < QQ; n += 256) s += expf(row[n] - m);
  red[tid] = s; __syncthreads();
  for (int off = 128; off > 0; off >>= 1) {
    if (tid < off) red[tid] += red[tid + off];
    __syncthreads();
  }
  s = red[0];
  float inv = 1.0f / s;
  for (int n = tid; n < QQ; n += 256) at[(size_t)n * KP + r] = f2bf(expf(row[n] - m) * inv);
}

// f0 = init * E[:,0] (unnormalized) into buf0 + per-slice row-sum partials
__global__ void k_init_step(const int* __restrict__ seq, const float* __restrict__ ip,
                            const float* __restrict__ Bt, unsigned short* __restrict__ buf0,
                            float* __restrict__ psum0) {
  int b = blockIdx.x, tid = threadIdx.x;
  __shared__ float sp[16];
  if (tid < 16) sp[tid] = 0.f;
  __syncthreads();
  int c0 = seq[b * TT];
  for (int q = tid; q < NP; q += 256) {
    float v = ip[q] * Bt[c0 * BTS + q];   // ip[q>=QQ]=0, Bt[.,q>=QQ]=0
    buf0[(size_t)b * KP + q] = f2bf(v);
    atomicAdd(&sp[q / 80], v);
  }
  __syncthreads();
  if (tid < 16) psum0[b * 16 + tid] = sp[tid];
}

__global__ __launch_bounds__(CBLK) void k_hmm_coop(
    const int* __restrict__ seq, const unsigned short* __restrict__ At,
    const float* __restrict__ Bt, unsigned short* __restrict__ bufB,
    float* __restrict__ psumB, unsigned* __restrict__ barc,
    float* __restrict__ out) {
  __shared__ u64 aldsq[MB * LQ];          // 34 KB: this block's alpha (bf16)
  __shared__ float inv_lds[MB];
  __shared__ int chars[MB];
  __shared__ float spart[MB][NWV];

  const int tid = threadIdx.x, wg = blockIdx.x;
  const int bb = wg % NBB, sl = wg / NBB; // 13 slice-WGs per batch block
  const int lane = tid & 63, wv = tid >> 6;
  const int lrow = lane >> 4, lcol = lane & 15;
  const int n0w = (sl * NWV + wv) * 16;   // this wave's 16-col tile base

  // --- prologue: pull this wave's At fragments into registers (step-invariant)
  u32x4 atr[KSTEPS];
  {
    const u32x4* atp = (const u32x4*)(At + (size_t)(n0w + lcol) * KP + 8 * lrow);
#pragma unroll
    for (int ks = 0; ks < KSTEPS; ++ks) atr[ks] = atp[4 * ks];
  }

  unsigned* bar = barc + bb * 16;
  float ll = 0.f;

  for (int t = 1; t < TT; ++t) {
    const int rd = (t - 1) % 3, wri = t % 3;
    const unsigned short* abuf = bufB + (size_t)rd * BUFN;
    unsigned short* wbuf = bufB + (size_t)wri * BUFN;

    // --- A: issue coherent loads (alpha block + psums), max MLP
    const u64* asrc = (const u64*)abuf + (size_t)bb * TOTQ + tid;
    u64 av[NLD], avx = 0;
#pragma unroll
    for (int j = 0; j < NLD; ++j) av[j] = ald8(asrc + j * CBLK);
    if (tid < NREM) avx = ald8(asrc + NLD * CBLK);
    u64 pq[8]; int ch = 0;
    if (tid < MB) {
      const u64* pp = (const u64*)(psumB + (size_t)rd * PSN + (bb * MB + tid) * 16);
#pragma unroll
      for (int j = 0; j < 8; ++j) pq[j] = ald8(pp + j);
      ch = seq[(bb * MB + tid) * TT + t];
    }

    // --- B: stage alpha into LDS (padded row stride)
#pragma unroll
    for (int j = 0; j < NLD; ++j) {
      int g = tid + j * CBLK;
      int r = g / RQ;
      aldsq[r * LQ + (g - r * RQ)] = av[j];
    }
    if (tid < NREM) {
      int g = tid + NLD * CBLK;
      int r = g / RQ;
      aldsq[r * LQ + (g - r * RQ)] = avx;
    }
    // --- C: scales + log-lik update
    if (tid < MB) {
      float s = 0.f;
#pragma unroll
      for (int j = 0; j < 8; ++j) {
        union { u64 q; float f[2]; } uu; uu.q = pq[j];
        s += uu.f[0] + uu.f[1];
      }
      ll += logf(s);
      inv_lds[tid] = 1.0f / s;
      chars[tid] = ch;
    }
    __syncthreads();  // LDS alpha + inv/chars ready

    // --- E: MFMA. arg0 = At frags (regs), arg1 = alpha frags (LDS).
    // D[row=n-within-tile via reg, col=batch-row via lane&15]
    const u32x4* ap = ((const u32x4*)aldsq) + lcol * (LQ / 2) + lrow;
    f32x4 acc = (f32x4){0.f, 0.f, 0.f, 0.f};
#pragma unroll
    for (int ks = 0; ks < KSTEPS; ++ks) {
      u32x4 af = ap[4 * ks];
      acc = __builtin_amdgcn_mfma_f32_16x16x32_bf16(
          __builtin_bit_cast(bf16x8, atr[ks]), __builtin_bit_cast(bf16x8, af),
          acc, 0, 0, 0);
    }

    // --- F: epilogue. Lane holds f[brow=lcol][n0w+4*lrow .. +3].
    const f32x4 ev = *(const f32x4*)(Bt + (size_t)chars[lcol] * BTS + n0w + 4 * lrow);
    const float inv = inv_lds[lcol];
    float rs = 0.f;
    u64 hv = 0;
#pragma unroll
    for (int i = 0; i < 4; ++i) {
      float v = acc[i] * ev[i] * inv;
      rs += v;
      hv |= (u64)f2bf(v) << (16 * i);
    }
    ast8((u64*)(wbuf + (size_t)(bb * MB + lcol) * KP + n0w + 4 * lrow), hv);
    rs += __shfl_xor(rs, 16);
    rs += __shfl_xor(rs, 32);
    if (lane < 16) spart[lane][wv] = rs;
    __syncthreads();  // spart ready; all waves' alpha stores drained here

    if (tid < MB) {
      float s5 = spart[tid][0] + spart[tid][1] + spart[tid][2] +
                 spart[tid][3] + spart[tid][4];
      ast4(psumB + (size_t)wri * PSN + (bb * MB + tid) * 16 + sl, s5);
    }
    // --- barrier: 13 arrivals per batch block, monotonic counter at L3
    if (tid == 0) {
      asm volatile("s_waitcnt vmcnt(0)" ::: "memory");  // wave-0 psum acked
      __hip_atomic_fetch_add(bar, 1u, __ATOMIC_RELAXED, __HIP_MEMORY_SCOPE_AGENT);
      const unsigned target = (unsigned)NSL * (unsigned)t;
      while (__hip_atomic_load(bar, __ATOMIC_RELAXED, __HIP_MEMORY_SCOPE_AGENT) < target)
        __builtin_amdgcn_s_sleep(1);
    }
    __syncthreads();
    asm volatile("" ::: "memory");
  }

  if (sl == 0 && tid < MB) {
    const u64* pp = (const u64*)(psumB + (size_t)((TT - 1) % 3) * PSN + (bb * MB + tid) * 16);
    float s = 0.f;
#pragma unroll
    for (int j = 0; j < 8; ++j) {
      union { u64 q; float f[2]; } uu; uu.q = ald8(pp + j);
      s += uu.f[0] + uu.f[1];
    }
    out[bb * MB + tid] = ll + logf(s);
  }
}

extern "C" void kernel_launch(void* const* d_in, const int* in_sizes, int n_in,
                              void* d_out, int out_size, void* d_ws, size_t ws_size,
                              hipStream_t stream) {
  const int* seq = (const int*)d_in[0];
  const float* Al = (const float*)d_in[1];
  const float* Bl = (const float*)d_in[2];
  const float* il = (const float*)d_in[3];
  float* out = (float*)d_out;

  char* ws = (char*)d_ws;
  unsigned short* At = (unsigned short*)ws;               // 1040*1056*2 = 2,196,480
  size_t off_bt = (size_t)NP * KP * 2;
  float* Bt = (float*)(ws + off_bt);                      // 26*1040*4 = 108,160
  size_t off_ip = off_bt + (size_t)SS * BTS * 4;
  float* ip = (float*)(ws + off_ip);                      // 1040*4
  size_t off_buf = off_ip + (size_t)NP * 4;
  unsigned short* bufB = (unsigned short*)(ws + off_buf); // 3*256*1056*2 = 1,622,016
  size_t off_ps = off_buf + (size_t)3 * BUFN * 2;
  float* psumB = (float*)(ws + off_ps);                   // 3*256*16*4 = 49,152
  size_t off_bar = off_ps + (size_t)3 * PSN * 4;
  unsigned* barc = (unsigned*)(ws + off_bar);             // 16 counters, 64B apart
  size_t total = off_bar + (size_t)NBB * 64;
  int n16 = (int)((total + 15) / 16);

  k_zero<<<(n16 + 255) / 256, 256, 0, stream>>>((u32x4*)ws, n16);
  k_prep_init<<<1, 1024, 0, stream>>>(il, ip);
  k_prep_B<<<(QQ + 255) / 256, 256, 0, stream>>>(Bl, Bt);
  k_prep_A<<<QQ, 256, 0, stream>>>(Al, At);
  k_init_step<<<NB, 256, 0, stream>>>(seq, ip, Bt, bufB, psumB);

  void* args[] = {(void*)&seq, (void*)&At, (void*)&Bt, (void*)&bufB,
                  (void*)&psumB, (void*)&barc, (void*)&out};
  hipLaunchCooperativeKernel((void*)k_hmm_coop, dim3(NBB * NSL), dim3(CBLK),
                             args, 0, stream);
}